// Round 2
// 1754.037 us; speedup vs baseline: 2.1558x; 2.1558x over previous
//
#include <hip/hip_runtime.h>
#include <hip/hip_bf16.h>

#define T_TOK 4096
#define NEXP 8
#define HID 2048
#define INTER 4096
#define NPAIR (2 * T_TOK)   // 8192 (token,expert) pairs total

typedef unsigned int u32;
typedef unsigned short u16;
typedef short s16x8 __attribute__((ext_vector_type(8)));
typedef float f32x4 __attribute__((ext_vector_type(4)));

#define LSTRIDE 40  // u16 per LDS row: 32 payload + 8 pad; all b128 ops land at the 8-way floor
#define BK 32
#define ASZ (128 * LSTRIDE)

__device__ __forceinline__ u16 f2bf(float a) {
  u32 u = __builtin_bit_cast(u32, a);
  return (u16)((u + 0x7fffu + ((u >> 16) & 1u)) >> 16);  // RNE, no NaN inputs
}
__device__ __forceinline__ u32 pk2(float a, float b) {
  return (u32)f2bf(a) | ((u32)f2bf(b) << 16);  // low u16 = a, high = b
}

// Raw barrier: waits LDS ops only, does NOT drain vmcnt -> global loads stay in
// flight across the barrier (the whole point of the 2-phase pipeline).
#define BARRIER() asm volatile("s_waitcnt lgkmcnt(0)\ns_barrier" ::: "memory")

// ---------------- routing ----------------
__global__ void zero_cnt_k(int* cnt) {
  if (threadIdx.x < NEXP) cnt[threadIdx.x] = 0;
}

__global__ void zero_out_k(float* out) {
  size_t i = ((size_t)blockIdx.x * blockDim.x + threadIdx.x) * 4;
  *(float4*)(out + i) = make_float4(0.f, 0.f, 0.f, 0.f);
}

__global__ void route_k(const float* __restrict__ logits, int* cnt,
                        int* eids, int* ranks, float* wts) {
  int t = blockIdx.x * blockDim.x + threadIdx.x;
  if (t >= T_TOK) return;
  float l[NEXP];
#pragma unroll
  for (int i = 0; i < NEXP; ++i) l[i] = logits[t * NEXP + i];
  int i0 = 0; float m0 = l[0];
#pragma unroll
  for (int i = 1; i < NEXP; ++i) if (l[i] > m0) { m0 = l[i]; i0 = i; }
  int i1 = -1; float m1 = -3.4e38f;
#pragma unroll
  for (int i = 0; i < NEXP; ++i) if (i != i0 && l[i] > m1) { m1 = l[i]; i1 = i; }
  float p1 = __expf(m1 - m0);
  float w0 = 1.f / (1.f + p1);
  float w1 = p1 * w0;
  int r0 = atomicAdd(&cnt[i0], 1);
  int r1 = atomicAdd(&cnt[i1], 1);
  eids[2 * t] = i0;  eids[2 * t + 1] = i1;
  ranks[2 * t] = r0; ranks[2 * t + 1] = r1;
  wts[2 * t] = w0;   wts[2 * t + 1] = w1;
}

__global__ void scan_k(const int* cnt, int* off) {
  if (threadIdx.x == 0 && blockIdx.x == 0) {
    int a = 0;
    for (int e = 0; e < NEXP; ++e) { off[e] = a; a += cnt[e]; }
  }
}

__global__ void place_k(const int* __restrict__ off, const int* __restrict__ eids,
                        const int* __restrict__ ranks, const float* __restrict__ wts,
                        int* __restrict__ tok, float* __restrict__ wgt) {
  int t = blockIdx.x * blockDim.x + threadIdx.x;
  if (t >= T_TOK) return;
#pragma unroll
  for (int s = 0; s < 2; ++s) {
    int e = eids[2 * t + s];
    int p = off[e] + ranks[2 * t + s];
    tok[p] = t;
    wgt[p] = wts[2 * t + s];
  }
}

// ---------------- GEMM1: A_buf = silu(Xg @ W1) * (Xg @ W3), bf16 out ----------------
// 512 threads, 8 waves (4 row x 2 col), tile 128 rows x 128 C-cols (64 gate + 64 up).
// 2-phase double-buffered pipeline: loads for tile t+2 issued at iter t, packed at
// iter t+1 after that iter's ds_read+MFMA -> one full iteration of latency cover.
// One raw barrier per iteration (dbuf: reads buf[t&1], writes buf[(t+1)&1]).
__global__ __launch_bounds__(512, 4) void gemm1_k(
    const float* __restrict__ X, const float* __restrict__ W13,
    const int* __restrict__ cnt, const int* __restrict__ off,
    const int* __restrict__ tok, u16* __restrict__ Abuf) {
  // XCD-chunk swizzle: 16384 blocks / 8 XCDs = 2048 -> XCD k gets one expert.
  const int id = ((blockIdx.x & 7) << 11) | ((int)blockIdx.x >> 3);
  const int rt = id & 31;
  const int ct = (id >> 5) & 63;
  const int e  = id >> 11;
  const int n_e = cnt[e];
  if (rt * 128 >= n_e) return;
  const int off_e = off[e];

  __shared__ __align__(16) u16 Ls[2][2][ASZ];   // [buf][A=0/B=1][row*LSTRIDE+k]

  const int tid = threadIdx.x;
  const int wid = tid >> 6;
  const int lane = tid & 63;
  const int q = lane >> 4;
  const int l15 = lane & 15;
  const int wr = wid >> 1;   // 0..3 -> rows 32*wr
  const int wc = wid & 1;    // 0..1 -> gate cols 32*wc, up cols 64+32*wc

  // A staging: 4 threads/row, 8 k each (one b128 slot per thread -> 8-way floor)
  const int arow = tid >> 2, aseg = tid & 3;
  int ridx = rt * 128 + arow;
  if (ridx >= n_e) ridx = n_e - 1;               // clamp; masked at store
  const float* aptr = X + (size_t)tok[off_e + ridx] * HID + aseg * 8;
  const int adoff = arow * LSTRIDE + aseg * 8;

  // B staging: 1 col/thread, 8 k each (transpose into Bs[n][k]; 8-way floor writes)
  const int c = tid & 127, ks = tid >> 7;
  const size_t colb = (c < 64) ? (size_t)(ct * 64 + c)
                               : (size_t)(INTER + ct * 64 + (c - 64));
  const float* bptr = W13 + (size_t)e * ((size_t)HID * (2 * INTER))
                    + (size_t)(ks * 8) * (2 * INTER) + colb;
  const int bdoff = c * LSTRIDE + ks * 8;

  const int afoff = (32 * wr + l15) * LSTRIDE + q * 8;
  const int bfoff = (32 * wc + l15) * LSTRIDE + q * 8;

  f32x4 acc[2][4];
#pragma unroll
  for (int i = 0; i < 2; ++i)
#pragma unroll
    for (int j = 0; j < 4; ++j) acc[i][j] = (f32x4){0.f, 0.f, 0.f, 0.f};

  float a_f[8], b_f[8];

#define G1_LOAD(k0_)                                                         \
  { const float* ap_ = aptr + (k0_);                                         \
    float4 t0_ = *(const float4*)ap_;                                        \
    float4 t1_ = *(const float4*)(ap_ + 4);                                  \
    a_f[0]=t0_.x; a_f[1]=t0_.y; a_f[2]=t0_.z; a_f[3]=t0_.w;                  \
    a_f[4]=t1_.x; a_f[5]=t1_.y; a_f[6]=t1_.z; a_f[7]=t1_.w;                  \
    const float* bp_ = bptr + (size_t)(k0_) * (2 * INTER);                   \
    b_f[0]=bp_[0*(size_t)(2*INTER)]; b_f[1]=bp_[1*(size_t)(2*INTER)];        \
    b_f[2]=bp_[2*(size_t)(2*INTER)]; b_f[3]=bp_[3*(size_t)(2*INTER)];        \
    b_f[4]=bp_[4*(size_t)(2*INTER)]; b_f[5]=bp_[5*(size_t)(2*INTER)];        \
    b_f[6]=bp_[6*(size_t)(2*INTER)]; b_f[7]=bp_[7*(size_t)(2*INTER)]; }

#define G1_PW(wb_)                                                           \
  { uint4 wa_ = make_uint4(pk2(a_f[0],a_f[1]), pk2(a_f[2],a_f[3]),           \
                           pk2(a_f[4],a_f[5]), pk2(a_f[6],a_f[7]));          \
    uint4 wv_ = make_uint4(pk2(b_f[0],b_f[1]), pk2(b_f[2],b_f[3]),           \
                           pk2(b_f[4],b_f[5]), pk2(b_f[6],b_f[7]));          \
    *(uint4*)&Ls[wb_][0][adoff] = wa_;                                       \
    *(uint4*)&Ls[wb_][1][bdoff] = wv_; }

#define G1_FM(rb_)                                                           \
  { const u16* Ab_ = Ls[rb_][0]; const u16* Bb_ = Ls[rb_][1];                \
    s16x8 af0 = *(const s16x8*)&Ab_[afoff];                                  \
    s16x8 af1 = *(const s16x8*)&Ab_[afoff + 16 * LSTRIDE];                   \
    s16x8 b0 = *(const s16x8*)&Bb_[bfoff];                                   \
    s16x8 b1 = *(const s16x8*)&Bb_[bfoff + 16 * LSTRIDE];                    \
    s16x8 b2 = *(const s16x8*)&Bb_[bfoff + 64 * LSTRIDE];                    \
    s16x8 b3 = *(const s16x8*)&Bb_[bfoff + 80 * LSTRIDE];                    \
    acc[0][0] = __builtin_amdgcn_mfma_f32_16x16x32_bf16(af0, b0, acc[0][0], 0, 0, 0); \
    acc[1][0] = __builtin_amdgcn_mfma_f32_16x16x32_bf16(af1, b0, acc[1][0], 0, 0, 0); \
    acc[0][1] = __builtin_amdgcn_mfma_f32_16x16x32_bf16(af0, b1, acc[0][1], 0, 0, 0); \
    acc[1][1] = __builtin_amdgcn_mfma_f32_16x16x32_bf16(af1, b1, acc[1][1], 0, 0, 0); \
    acc[0][2] = __builtin_amdgcn_mfma_f32_16x16x32_bf16(af0, b2, acc[0][2], 0, 0, 0); \
    acc[1][2] = __builtin_amdgcn_mfma_f32_16x16x32_bf16(af1, b2, acc[1][2], 0, 0, 0); \
    acc[0][3] = __builtin_amdgcn_mfma_f32_16x16x32_bf16(af0, b3, acc[0][3], 0, 0, 0); \
    acc[1][3] = __builtin_amdgcn_mfma_f32_16x16x32_bf16(af1, b3, acc[1][3], 0, 0, 0); }

  const int NT = HID / BK;  // 64
  G1_LOAD(0);
  G1_PW(0);
  G1_LOAD(BK);              // tile 1 in flight across the barrier
  BARRIER();
#pragma unroll 2
  for (int t = 0; t < NT; ++t) {
    G1_FM(t & 1);
    if (t + 1 < NT) {
      G1_PW((t + 1) & 1);   // compiler inserts the vmcnt wait right here
      int kn = (t + 2) * BK;
      if (kn > HID - BK) kn = HID - BK;   // tail: redundant but in-bounds
      G1_LOAD(kn);
      BARRIER();
    }
  }

  // epilogue: a = silu(gate) * up ; gate = acc[rf][0..1], up = acc[rf][2..3]
  const int rb = rt * 128 + 32 * wr + q * 4;
#pragma unroll
  for (int rf = 0; rf < 2; ++rf) {
#pragma unroll
    for (int r = 0; r < 4; ++r) {
      const int grow = rb + 16 * rf + r;
      if (grow < n_e) {
        u16* ad = Abuf + (size_t)(off_e + grow) * INTER + (ct * 64 + 32 * wc + l15);
        float g0 = acc[rf][0][r], u0 = acc[rf][2][r];
        float g1 = acc[rf][1][r], u1 = acc[rf][3][r];
        ad[0]  = f2bf(g0 / (1.f + __expf(-g0)) * u0);
        ad[16] = f2bf(g1 / (1.f + __expf(-g1)) * u1);
      }
    }
  }
#undef G1_LOAD
#undef G1_PW
#undef G1_FM
}

// ---------------- GEMM2: out += w * (A_buf @ W2) ----------------
// Same 2-phase pipeline; A is already bf16 (one uint4 load, no pack).
__global__ __launch_bounds__(512, 4) void gemm2_k(
    const u16* __restrict__ Abuf, const float* __restrict__ W2,
    const int* __restrict__ cnt, const int* __restrict__ off,
    const int* __restrict__ tok, const float* __restrict__ wgt,
    float* __restrict__ out) {
  // 4096 blocks / 8 XCDs = 512 -> XCD k gets one expert.
  const int id = ((blockIdx.x & 7) << 9) | ((int)blockIdx.x >> 3);
  const int rt = id & 31;
  const int ct = (id >> 5) & 15;
  const int e  = id >> 9;
  const int n_e = cnt[e];
  if (rt * 128 >= n_e) return;
  const int off_e = off[e];

  __shared__ __align__(16) u16 Ls[2][2][ASZ];

  const int tid = threadIdx.x;
  const int wid = tid >> 6;
  const int lane = tid & 63;
  const int q = lane >> 4;
  const int l15 = lane & 15;
  const int wr = wid >> 1;
  const int wc = wid & 1;    // cols 64*wc .. +64

  const int arow = tid >> 2, aseg = tid & 3;
  int ridx = rt * 128 + arow;
  if (ridx >= n_e) ridx = n_e - 1;
  const u16* aptr = Abuf + (size_t)(off_e + ridx) * INTER + aseg * 8;
  const int adoff = arow * LSTRIDE + aseg * 8;

  const int c = tid & 127, ks = tid >> 7;
  const float* bptr = W2 + (size_t)e * ((size_t)INTER * HID)
                    + (size_t)(ks * 8) * HID + (ct * 128 + c);
  const int bdoff = c * LSTRIDE + ks * 8;

  const int afoff = (32 * wr + l15) * LSTRIDE + q * 8;
  const int bfoff = (64 * wc + l15) * LSTRIDE + q * 8;

  f32x4 acc[2][4];
#pragma unroll
  for (int i = 0; i < 2; ++i)
#pragma unroll
    for (int j = 0; j < 4; ++j) acc[i][j] = (f32x4){0.f, 0.f, 0.f, 0.f};

  uint4 a_u;
  float b_f[8];

#define G2_LOAD(k0_)                                                         \
  { a_u = *(const uint4*)(aptr + (k0_));                                     \
    const float* bp_ = bptr + (size_t)(k0_) * HID;                           \
    b_f[0]=bp_[0*(size_t)HID]; b_f[1]=bp_[1*(size_t)HID];                    \
    b_f[2]=bp_[2*(size_t)HID]; b_f[3]=bp_[3*(size_t)HID];                    \
    b_f[4]=bp_[4*(size_t)HID]; b_f[5]=bp_[5*(size_t)HID];                    \
    b_f[6]=bp_[6*(size_t)HID]; b_f[7]=bp_[7*(size_t)HID]; }

#define G2_PW(wb_)                                                           \
  { uint4 wv_ = make_uint4(pk2(b_f[0],b_f[1]), pk2(b_f[2],b_f[3]),           \
                           pk2(b_f[4],b_f[5]), pk2(b_f[6],b_f[7]));          \
    *(uint4*)&Ls[wb_][0][adoff] = a_u;                                       \
    *(uint4*)&Ls[wb_][1][bdoff] = wv_; }

#define G2_FM(rb_)                                                           \
  { const u16* Ab_ = Ls[rb_][0]; const u16* Bb_ = Ls[rb_][1];                \
    s16x8 af0 = *(const s16x8*)&Ab_[afoff];                                  \
    s16x8 af1 = *(const s16x8*)&Ab_[afoff + 16 * LSTRIDE];                   \
    s16x8 b0 = *(const s16x8*)&Bb_[bfoff];                                   \
    s16x8 b1 = *(const s16x8*)&Bb_[bfoff + 16 * LSTRIDE];                    \
    s16x8 b2 = *(const s16x8*)&Bb_[bfoff + 32 * LSTRIDE];                    \
    s16x8 b3 = *(const s16x8*)&Bb_[bfoff + 48 * LSTRIDE];                    \
    acc[0][0] = __builtin_amdgcn_mfma_f32_16x16x32_bf16(af0, b0, acc[0][0], 0, 0, 0); \
    acc[1][0] = __builtin_amdgcn_mfma_f32_16x16x32_bf16(af1, b0, acc[1][0], 0, 0, 0); \
    acc[0][1] = __builtin_amdgcn_mfma_f32_16x16x32_bf16(af0, b1, acc[0][1], 0, 0, 0); \
    acc[1][1] = __builtin_amdgcn_mfma_f32_16x16x32_bf16(af1, b1, acc[1][1], 0, 0, 0); \
    acc[0][2] = __builtin_amdgcn_mfma_f32_16x16x32_bf16(af0, b2, acc[0][2], 0, 0, 0); \
    acc[1][2] = __builtin_amdgcn_mfma_f32_16x16x32_bf16(af1, b2, acc[1][2], 0, 0, 0); \
    acc[0][3] = __builtin_amdgcn_mfma_f32_16x16x32_bf16(af0, b3, acc[0][3], 0, 0, 0); \
    acc[1][3] = __builtin_amdgcn_mfma_f32_16x16x32_bf16(af1, b3, acc[1][3], 0, 0, 0); }

  const int NT = INTER / BK;  // 128
  G2_LOAD(0);
  G2_PW(0);
  G2_LOAD(BK);
  BARRIER();
#pragma unroll 2
  for (int t = 0; t < NT; ++t) {
    G2_FM(t & 1);
    if (t + 1 < NT) {
      G2_PW((t + 1) & 1);
      int kn = (t + 2) * BK;
      if (kn > INTER - BK) kn = INTER - BK;
      G2_LOAD(kn);
      BARRIER();
    }
  }

  const int rb = rt * 128 + 32 * wr + q * 4;
#pragma unroll
  for (int rf = 0; rf < 2; ++rf) {
#pragma unroll
    for (int r = 0; r < 4; ++r) {
      const int grow = rb + 16 * rf + r;
      if (grow < n_e) {
        const int p = off_e + grow;
        const int tkn = tok[p];
        const float w = wgt[p];
        float* orow = out + (size_t)tkn * HID + (ct * 128 + 64 * wc + l15);
        atomicAdd(orow + 0,  w * acc[rf][0][r]);
        atomicAdd(orow + 16, w * acc[rf][1][r]);
        atomicAdd(orow + 32, w * acc[rf][2][r]);
        atomicAdd(orow + 48, w * acc[rf][3][r]);
      }
    }
  }
#undef G2_LOAD
#undef G2_PW
#undef G2_FM
}

extern "C" void kernel_launch(void* const* d_in, const int* in_sizes, int n_in,
                              void* d_out, int out_size, void* d_ws, size_t ws_size,
                              hipStream_t stream) {
  const float* X      = (const float*)d_in[0];   // [T, H]
  const float* logits = (const float*)d_in[1];   // [T, E]
  const float* W13    = (const float*)d_in[2];   // [E, H, 2I]
  const float* W2     = (const float*)d_in[3];   // [E, I, H]
  // d_in[4] = top_k (=2, hard-coded)
  float* out = (float*)d_out;

  char* ws = (char*)d_ws;
  int* cnt    = (int*)ws;                        // 8
  int* off    = cnt + NEXP;                      // 8
  int* eids   = off + NEXP;                      // 2T
  int* ranks  = eids + NPAIR;                    // 2T
  float* wts  = (float*)(ranks + NPAIR);         // 2T
  int* tokA   = (int*)(wts + NPAIR);             // 8192
  float* wgtA = (float*)(tokA + NPAIR);          // 8192
  u16* Abuf   = (u16*)(ws + (1 << 20));          // [8192, INTER] bf16 = 64 MiB

  zero_cnt_k<<<1, 64, 0, stream>>>(cnt);
  zero_out_k<<<(T_TOK * HID) / 1024, 256, 0, stream>>>(out);
  route_k<<<T_TOK / 256, 256, 0, stream>>>(logits, cnt, eids, ranks, wts);
  scan_k<<<1, 64, 0, stream>>>(cnt, off);
  place_k<<<T_TOK / 256, 256, 0, stream>>>(off, eids, ranks, wts, tokA, wgtA);
  gemm1_k<<<NEXP * 64 * 32, 512, 0, stream>>>(X, W13, cnt, off, tokA, Abuf);
  gemm2_k<<<NEXP * 16 * 32, 512, 0, stream>>>(Abuf, W2, cnt, off, tokA, wgtA, out);
}

// Round 3
// 1655.239 us; speedup vs baseline: 2.2844x; 1.0597x over previous
//
#include <hip/hip_runtime.h>
#include <hip/hip_bf16.h>

#define T_TOK 4096
#define NEXP 8
#define HID 2048
#define INTER 4096
#define NPAIR (2 * T_TOK)   // 8192 (token,expert) pairs total

typedef unsigned int u32;
typedef unsigned short u16;
typedef short s16x8 __attribute__((ext_vector_type(8)));
typedef float f32x4 __attribute__((ext_vector_type(4)));

#define LSTRIDE 40  // u16 per LDS row: 32 payload + 8 pad
#define BK 32
#define ASZ (128 * LSTRIDE)

__device__ __forceinline__ u16 f2bf(float a) {
  u32 u = __builtin_bit_cast(u32, a);
  return (u16)((u + 0x7fffu + ((u >> 16) & 1u)) >> 16);  // RNE, no NaN inputs
}
__device__ __forceinline__ u32 pk2(float a, float b) {
  return (u32)f2bf(a) | ((u32)f2bf(b) << 16);  // low u16 = a, high = b
}

// Raw barrier: waits LDS ops only, does NOT drain vmcnt -> global loads stay in
// flight across the barrier.
#define BARRIER() asm volatile("s_waitcnt lgkmcnt(0)\ns_barrier" ::: "memory")

// ---------------- routing ----------------
__global__ void zero_cnt_k(int* cnt) {
  if (threadIdx.x < NEXP) cnt[threadIdx.x] = 0;
}

__global__ void zero_out_k(float* out) {
  size_t i = ((size_t)blockIdx.x * blockDim.x + threadIdx.x) * 4;
  *(float4*)(out + i) = make_float4(0.f, 0.f, 0.f, 0.f);
}

__global__ void route_k(const float* __restrict__ logits, int* cnt,
                        int* eids, int* ranks, float* wts) {
  int t = blockIdx.x * blockDim.x + threadIdx.x;
  if (t >= T_TOK) return;
  float l[NEXP];
#pragma unroll
  for (int i = 0; i < NEXP; ++i) l[i] = logits[t * NEXP + i];
  int i0 = 0; float m0 = l[0];
#pragma unroll
  for (int i = 1; i < NEXP; ++i) if (l[i] > m0) { m0 = l[i]; i0 = i; }
  int i1 = -1; float m1 = -3.4e38f;
#pragma unroll
  for (int i = 0; i < NEXP; ++i) if (i != i0 && l[i] > m1) { m1 = l[i]; i1 = i; }
  float p1 = __expf(m1 - m0);
  float w0 = 1.f / (1.f + p1);
  float w1 = p1 * w0;
  int r0 = atomicAdd(&cnt[i0], 1);
  int r1 = atomicAdd(&cnt[i1], 1);
  eids[2 * t] = i0;  eids[2 * t + 1] = i1;
  ranks[2 * t] = r0; ranks[2 * t + 1] = r1;
  wts[2 * t] = w0;   wts[2 * t + 1] = w1;
}

__global__ void scan_k(const int* cnt, int* off) {
  if (threadIdx.x == 0 && blockIdx.x == 0) {
    int a = 0;
    for (int e = 0; e < NEXP; ++e) { off[e] = a; a += cnt[e]; }
  }
}

__global__ void place_k(const int* __restrict__ off, const int* __restrict__ eids,
                        const int* __restrict__ ranks, const float* __restrict__ wts,
                        int* __restrict__ tok, float* __restrict__ wgt) {
  int t = blockIdx.x * blockDim.x + threadIdx.x;
  if (t >= T_TOK) return;
#pragma unroll
  for (int s = 0; s < 2; ++s) {
    int e = eids[2 * t + s];
    int p = off[e] + ranks[2 * t + s];
    tok[p] = t;
    wgt[p] = wts[2 * t + s];
  }
}

// ---------------- bf16 pre-conversion ----------------
// convx: X [T][H] f32 -> Xbf same layout bf16 (k-contiguous rows).
__global__ void convx_k(const float* __restrict__ X, u16* __restrict__ Xbf) {
  size_t i = (size_t)blockIdx.x * blockDim.x + threadIdx.x;  // uint4 chunk id
  float4 v0 = ((const float4*)X)[i * 2];
  float4 v1 = ((const float4*)X)[i * 2 + 1];
  uint4 w = make_uint4(pk2(v0.x, v0.y), pk2(v0.z, v0.w),
                       pk2(v1.x, v1.y), pk2(v1.z, v1.w));
  ((uint4*)Xbf)[i] = w;
}

// Transposing converter: in [K rows][N cols] f32 (row stride = nstride) per expert
// -> out tiled chunks: chunk[ko][n][8k] bf16, chunk idx = ko*N + n (per expert).
// Tile = 64 k x 32 n per block, 256 threads.
// grid: e * ktiles * ntiles.
template <int KDIM, int NDIM>
__global__ void convw_k(const float* __restrict__ src0, u16* __restrict__ dst0) {
  const int ntiles = NDIM / 32;
  const int ktiles = KDIM / 64;
  const int b = blockIdx.x;
  const int nt = b % ntiles;
  const int kt = (b / ntiles) % ktiles;
  const int e  = b / (ntiles * ktiles);
  const float* src = src0 + (size_t)e * KDIM * NDIM + (size_t)(kt * 64) * NDIM + nt * 32;
  uint4* dst = (uint4*)dst0 + (size_t)e * (KDIM / 8) * NDIM;

  __shared__ u32 Lt[32][36];  // [n][k-pair], pad keeps b128 reads aligned/spread

  const int t = threadIdx.x;
  const int r = t >> 3;    // row-pair 0..31 -> k rows 2r,2r+1
  const int c4 = t & 7;    // float4 col 0..7 -> n = c4*4..+3
  float4 v0 = ((const float4*)(src + (size_t)(2 * r) * NDIM))[c4];
  float4 v1 = ((const float4*)(src + (size_t)(2 * r + 1) * NDIM))[c4];
  Lt[c4 * 4 + 0][r] = pk2(v0.x, v1.x);
  Lt[c4 * 4 + 1][r] = pk2(v0.y, v1.y);
  Lt[c4 * 4 + 2][r] = pk2(v0.z, v1.z);
  Lt[c4 * 4 + 3][r] = pk2(v0.w, v1.w);
  __syncthreads();
  const int n = t >> 3;    // 0..31
  const int q = t & 7;     // k-octet within tile 0..7
  uint4 w = *(const uint4*)&Lt[n][q * 4];
  dst[(size_t)(kt * 8 + q) * NDIM + nt * 32 + n] = w;
}

// ---------------- GEMM1: A_buf = silu(Xg @ W1) * (Xg @ W3), bf16 tiled out ----------
// 512 threads, 8 waves (4 row x 2 col), tile 128 rows x 128 C-cols (64 gate + 64 up).
// Depth-2 reg-staged pipeline, lgkm-only barrier (loads stay in flight).
__global__ __launch_bounds__(512, 4) void gemm1_k(
    const u16* __restrict__ Xbf, const u16* __restrict__ W13T,
    const int* __restrict__ cnt, const int* __restrict__ off,
    const int* __restrict__ tok, u16* __restrict__ Abuf) {
  // XCD-chunk swizzle: 16384 blocks / 8 XCDs = 2048 -> XCD k gets one expert.
  const int id = ((blockIdx.x & 7) << 11) | ((int)blockIdx.x >> 3);
  const int rt = id & 31;
  const int ct = (id >> 5) & 63;
  const int e  = id >> 11;
  const int n_e = cnt[e];
  if (rt * 128 >= n_e) return;
  const int off_e = off[e];

  __shared__ __align__(16) u16 Ls[2][2][ASZ];   // [buf][A=0/B=1][row*LSTRIDE+k]

  const int tid = threadIdx.x;
  const int wid = tid >> 6;
  const int lane = tid & 63;
  const int q = lane >> 4;
  const int l15 = lane & 15;
  const int wr = wid >> 1;   // 0..3 -> rows 32*wr
  const int wc = wid & 1;    // 0..1 -> gate cols 32*wc, up cols 64+32*wc

  // A staging: 4 threads/row, one uint4 (8 bf16) each
  const int arow = tid >> 2, aseg = tid & 3;
  int ridx = rt * 128 + arow;
  if (ridx >= n_e) ridx = n_e - 1;               // clamp; masked at store
  const u16* aptr = Xbf + (size_t)tok[off_e + ridx] * HID + aseg * 8;
  const int adoff = arow * LSTRIDE + aseg * 8;

  // B staging: 1 col/thread, one uint4 (8 bf16 k) from tiled W13T
  const int c = tid & 127, ks = tid >> 7;
  const int colb = (c < 64) ? (ct * 64 + c) : (INTER + ct * 64 + (c - 64));
  const uint4* bbase = (const uint4*)W13T + (size_t)e * ((size_t)(HID / 8) * (2 * INTER))
                     + (size_t)ks * (2 * INTER) + colb;
  const int bdoff = c * LSTRIDE + ks * 8;

  const int afoff = (32 * wr + l15) * LSTRIDE + q * 8;
  const int bfoff = (32 * wc + l15) * LSTRIDE + q * 8;

  f32x4 acc[2][4];
#pragma unroll
  for (int i = 0; i < 2; ++i)
#pragma unroll
    for (int j = 0; j < 4; ++j) acc[i][j] = (f32x4){0.f, 0.f, 0.f, 0.f};

  uint4 a_u, b_u;

#define G1_LOAD(k0_)                                                         \
  { a_u = *(const uint4*)(aptr + (k0_));                                     \
    b_u = bbase[(size_t)((k0_) >> 3) * (2 * INTER)]; }

#define G1_PW(wb_)                                                           \
  { *(uint4*)&Ls[wb_][0][adoff] = a_u;                                       \
    *(uint4*)&Ls[wb_][1][bdoff] = b_u; }

#define G1_FM(rb_)                                                           \
  { const u16* Ab_ = Ls[rb_][0]; const u16* Bb_ = Ls[rb_][1];                \
    s16x8 af0 = *(const s16x8*)&Ab_[afoff];                                  \
    s16x8 af1 = *(const s16x8*)&Ab_[afoff + 16 * LSTRIDE];                   \
    s16x8 b0 = *(const s16x8*)&Bb_[bfoff];                                   \
    s16x8 b1 = *(const s16x8*)&Bb_[bfoff + 16 * LSTRIDE];                    \
    s16x8 b2 = *(const s16x8*)&Bb_[bfoff + 64 * LSTRIDE];                    \
    s16x8 b3 = *(const s16x8*)&Bb_[bfoff + 80 * LSTRIDE];                    \
    acc[0][0] = __builtin_amdgcn_mfma_f32_16x16x32_bf16(af0, b0, acc[0][0], 0, 0, 0); \
    acc[1][0] = __builtin_amdgcn_mfma_f32_16x16x32_bf16(af1, b0, acc[1][0], 0, 0, 0); \
    acc[0][1] = __builtin_amdgcn_mfma_f32_16x16x32_bf16(af0, b1, acc[0][1], 0, 0, 0); \
    acc[1][1] = __builtin_amdgcn_mfma_f32_16x16x32_bf16(af1, b1, acc[1][1], 0, 0, 0); \
    acc[0][2] = __builtin_amdgcn_mfma_f32_16x16x32_bf16(af0, b2, acc[0][2], 0, 0, 0); \
    acc[1][2] = __builtin_amdgcn_mfma_f32_16x16x32_bf16(af1, b2, acc[1][2], 0, 0, 0); \
    acc[0][3] = __builtin_amdgcn_mfma_f32_16x16x32_bf16(af0, b3, acc[0][3], 0, 0, 0); \
    acc[1][3] = __builtin_amdgcn_mfma_f32_16x16x32_bf16(af1, b3, acc[1][3], 0, 0, 0); }

  const int NT = HID / BK;  // 64
  G1_LOAD(0);
  G1_PW(0);
  G1_LOAD(BK);              // tile 1 in flight across the barrier
  BARRIER();
#pragma unroll 2
  for (int t = 0; t < NT; ++t) {
    G1_FM(t & 1);
    if (t + 1 < NT) {
      G1_PW((t + 1) & 1);   // compiler inserts the vmcnt wait right here
      int kn = (t + 2) * BK;
      if (kn > HID - BK) kn = HID - BK;   // tail: redundant but in-bounds
      G1_LOAD(kn);
      BARRIER();
    }
  }

  // epilogue: a = silu(gate) * up ; gate = acc[rf][0..1], up = acc[rf][2..3]
  // Abuf is k-octet-tiled: elem (p, n) at ((n>>3)*NPAIR + p)*8 + (n&7)
  const int rb = rt * 128 + 32 * wr + q * 4;
  const int nb = ct * 64 + 32 * wc + l15;
  const size_t cb0 = (size_t)(nb >> 3) * NPAIR;
  const int nrem = nb & 7;
#pragma unroll
  for (int rf = 0; rf < 2; ++rf) {
#pragma unroll
    for (int r = 0; r < 4; ++r) {
      const int grow = rb + 16 * rf + r;
      if (grow < n_e) {
        const size_t p = (size_t)(off_e + grow);
        float g0 = acc[rf][0][r], u0 = acc[rf][2][r];
        float g1 = acc[rf][1][r], u1 = acc[rf][3][r];
        Abuf[(cb0 + p) * 8 + nrem]              = f2bf(g0 / (1.f + __expf(-g0)) * u0);
        Abuf[(cb0 + 2 * NPAIR + p) * 8 + nrem]  = f2bf(g1 / (1.f + __expf(-g1)) * u1);
      }
    }
  }
#undef G1_LOAD
#undef G1_PW
#undef G1_FM
}

// ---------------- GEMM2: out += w * (A_buf @ W2) ----------------
__global__ __launch_bounds__(512, 4) void gemm2_k(
    const u16* __restrict__ Abuf, const u16* __restrict__ W2T,
    const int* __restrict__ cnt, const int* __restrict__ off,
    const int* __restrict__ tok, const float* __restrict__ wgt,
    float* __restrict__ out) {
  // 4096 blocks / 8 XCDs = 512 -> XCD k gets one expert.
  const int id = ((blockIdx.x & 7) << 9) | ((int)blockIdx.x >> 3);
  const int rt = id & 31;
  const int ct = (id >> 5) & 15;
  const int e  = id >> 9;
  const int n_e = cnt[e];
  if (rt * 128 >= n_e) return;
  const int off_e = off[e];

  __shared__ __align__(16) u16 Ls[2][2][ASZ];

  const int tid = threadIdx.x;
  const int wid = tid >> 6;
  const int lane = tid & 63;
  const int q = lane >> 4;
  const int l15 = lane & 15;
  const int wr = wid >> 1;
  const int wc = wid & 1;    // cols 64*wc .. +64

  const int arow = tid >> 2, aseg = tid & 3;
  int ridx = rt * 128 + arow;
  if (ridx >= n_e) ridx = n_e - 1;
  const size_t p_stage = (size_t)(off_e + ridx);
  const uint4* abase = (const uint4*)Abuf + (size_t)aseg * NPAIR + p_stage;
  const int adoff = arow * LSTRIDE + aseg * 8;

  const int c = tid & 127, ks = tid >> 7;
  const uint4* bbase = (const uint4*)W2T + (size_t)e * ((size_t)(INTER / 8) * HID)
                     + (size_t)ks * HID + (ct * 128 + c);
  const int bdoff = c * LSTRIDE + ks * 8;

  const int afoff = (32 * wr + l15) * LSTRIDE + q * 8;
  const int bfoff = (64 * wc + l15) * LSTRIDE + q * 8;

  f32x4 acc[2][4];
#pragma unroll
  for (int i = 0; i < 2; ++i)
#pragma unroll
    for (int j = 0; j < 4; ++j) acc[i][j] = (f32x4){0.f, 0.f, 0.f, 0.f};

  uint4 a_u, b_u;

#define G2_LOAD(k0_)                                                         \
  { a_u = abase[(size_t)((k0_) >> 3) * NPAIR];                               \
    b_u = bbase[(size_t)((k0_) >> 3) * HID]; }

#define G2_PW(wb_)                                                           \
  { *(uint4*)&Ls[wb_][0][adoff] = a_u;                                       \
    *(uint4*)&Ls[wb_][1][bdoff] = b_u; }

#define G2_FM(rb_)                                                           \
  { const u16* Ab_ = Ls[rb_][0]; const u16* Bb_ = Ls[rb_][1];                \
    s16x8 af0 = *(const s16x8*)&Ab_[afoff];                                  \
    s16x8 af1 = *(const s16x8*)&Ab_[afoff + 16 * LSTRIDE];                   \
    s16x8 b0 = *(const s16x8*)&Bb_[bfoff];                                   \
    s16x8 b1 = *(const s16x8*)&Bb_[bfoff + 16 * LSTRIDE];                    \
    s16x8 b2 = *(const s16x8*)&Bb_[bfoff + 32 * LSTRIDE];                    \
    s16x8 b3 = *(const s16x8*)&Bb_[bfoff + 48 * LSTRIDE];                    \
    acc[0][0] = __builtin_amdgcn_mfma_f32_16x16x32_bf16(af0, b0, acc[0][0], 0, 0, 0); \
    acc[1][0] = __builtin_amdgcn_mfma_f32_16x16x32_bf16(af1, b0, acc[1][0], 0, 0, 0); \
    acc[0][1] = __builtin_amdgcn_mfma_f32_16x16x32_bf16(af0, b1, acc[0][1], 0, 0, 0); \
    acc[1][1] = __builtin_amdgcn_mfma_f32_16x16x32_bf16(af1, b1, acc[1][1], 0, 0, 0); \
    acc[0][2] = __builtin_amdgcn_mfma_f32_16x16x32_bf16(af0, b2, acc[0][2], 0, 0, 0); \
    acc[1][2] = __builtin_amdgcn_mfma_f32_16x16x32_bf16(af1, b2, acc[1][2], 0, 0, 0); \
    acc[0][3] = __builtin_amdgcn_mfma_f32_16x16x32_bf16(af0, b3, acc[0][3], 0, 0, 0); \
    acc[1][3] = __builtin_amdgcn_mfma_f32_16x16x32_bf16(af1, b3, acc[1][3], 0, 0, 0); }

  const int NT = INTER / BK;  // 128
  G2_LOAD(0);
  G2_PW(0);
  G2_LOAD(BK);
  BARRIER();
#pragma unroll 2
  for (int t = 0; t < NT; ++t) {
    G2_FM(t & 1);
    if (t + 1 < NT) {
      G2_PW((t + 1) & 1);
      int kn = (t + 2) * BK;
      if (kn > INTER - BK) kn = INTER - BK;
      G2_LOAD(kn);
      BARRIER();
    }
  }

  const int rb = rt * 128 + 32 * wr + q * 4;
#pragma unroll
  for (int rf = 0; rf < 2; ++rf) {
#pragma unroll
    for (int r = 0; r < 4; ++r) {
      const int grow = rb + 16 * rf + r;
      if (grow < n_e) {
        const int pp = off_e + grow;
        const int tkn = tok[pp];
        const float w = wgt[pp];
        float* orow = out + (size_t)tkn * HID + (ct * 128 + 64 * wc + l15);
        atomicAdd(orow + 0,  w * acc[rf][0][r]);
        atomicAdd(orow + 16, w * acc[rf][1][r]);
        atomicAdd(orow + 32, w * acc[rf][2][r]);
        atomicAdd(orow + 48, w * acc[rf][3][r]);
      }
    }
  }
#undef G2_LOAD
#undef G2_PW
#undef G2_FM
}

extern "C" void kernel_launch(void* const* d_in, const int* in_sizes, int n_in,
                              void* d_out, int out_size, void* d_ws, size_t ws_size,
                              hipStream_t stream) {
  const float* X      = (const float*)d_in[0];   // [T, H]
  const float* logits = (const float*)d_in[1];   // [T, E]
  const float* W13    = (const float*)d_in[2];   // [E, H, 2I]
  const float* W2     = (const float*)d_in[3];   // [E, I, H]
  float* out = (float*)d_out;

  char* ws = (char*)d_ws;
  int* cnt    = (int*)ws;                        // 8
  int* off    = cnt + NEXP;                      // 8
  int* eids   = off + NEXP;                      // 2T
  int* ranks  = eids + NPAIR;                    // 2T
  float* wts  = (float*)(ranks + NPAIR);         // 2T
  int* tokA   = (int*)(wts + NPAIR);             // 8192
  float* wgtA = (float*)(tokA + NPAIR);          // 8192
  u16* Xbf  = (u16*)(ws + ((size_t)1 << 20));    // 16 MiB  [1,17) MB
  u16* Abuf = (u16*)(ws + ((size_t)24 << 20));   // 64 MiB  [24,88) MB (tiled)
  u16* W13T = (u16*)(ws + ((size_t)96 << 20));   // 256 MiB [96,352) MB (tiled)
  u16* W2T  = W13T;                              // 128 MiB, reuses W13T after gemm1

  zero_cnt_k<<<1, 64, 0, stream>>>(cnt);
  zero_out_k<<<(T_TOK * HID) / 1024, 256, 0, stream>>>(out);
  route_k<<<T_TOK / 256, 256, 0, stream>>>(logits, cnt, eids, ranks, wts);
  scan_k<<<1, 64, 0, stream>>>(cnt, off);
  place_k<<<T_TOK / 256, 256, 0, stream>>>(off, eids, ranks, wts, tokA, wgtA);
  convx_k<<<(T_TOK * HID / 8) / 256, 256, 0, stream>>>(X, Xbf);
  convw_k<HID, 2 * INTER><<<NEXP * (HID / 64) * (2 * INTER / 32), 256, 0, stream>>>(W13, W13T);
  gemm1_k<<<NEXP * 64 * 32, 512, 0, stream>>>(Xbf, W13T, cnt, off, tokA, Abuf);
  convw_k<INTER, HID><<<NEXP * (INTER / 64) * (HID / 32), 256, 0, stream>>>(W2, W2T);
  gemm2_k<<<NEXP * 16 * 32, 512, 0, stream>>>(Abuf, W2T, cnt, off, tokA, wgtA, out);
}